// Round 4
// baseline (254.538 us; speedup 1.0000x reference)
//
#include <hip/hip_runtime.h>

#define B_ 16
#define K_ 20
#define H_ 256
#define W_ 256
#define HW_ (H_*W_)
#define BK_ (B_*K_)
#define TH_ 16          // output rows per WAVE strip (16 strips/image)
#define KT_ 5           // classes per stats block
#define SCH_ 16         // stats row-chunks (16 rows each) -> 1024 blocks
#define NBLK_FUSED_ (4*K_*B_)   // fused grid = 1280 blocks

// ws layout (floats): statsP [SCH_][4][BK_] | ndP [NBLK][2] | cnt  (~92 KB)
#define WS_ND_   (SCH_*4*BK_)
#define WS_CNT_  (WS_ND_ + 2*NBLK_FUSED_)

// Gaussian taps exp(-d^2/50), d=1..4 (tap symmetry: 4 distinct + center 1.0)
#define G1T 0.980198673f
#define G2T 0.923116346f
#define G3T 0.835270211f
#define G4T 0.726149037f

__device__ __forceinline__ float4 zero4() { return make_float4(0.f, 0.f, 0.f, 0.f); }

// ---------------------------------------------------------------------------
// stats_k: per-(b,k) sums of labels and labels*inputs_c as per-chunk partials.
// grid (SCH_=16, K_/KT_=4, B_=16) = 1024 blocks (4/CU -> latency hidden).
// All 8 float4 loads of an iteration are batched before the FMA chains.
// ---------------------------------------------------------------------------
__global__ __launch_bounds__(256) void stats_k(const float* __restrict__ labels,
                                               const float* __restrict__ inputs,
                                               float* __restrict__ ws) {
    const int x = threadIdx.x;
    const int chunk = blockIdx.x;   // 16 rows each
    const int kt = blockIdx.y;
    const int b  = blockIdx.z;
    const int k0 = kt * KT_;
    if (chunk == 0 && kt == 0 && b == 0 && x == 0)
        ((unsigned*)(ws + WS_CNT_))[0] = 0u;   // reset fused completion counter

    const int cbase = chunk * (16 * W_ / 4);   // float4 units
    const float4* in0 = (const float4*)inputs + (size_t)b * 3 * (HW_/4) + cbase;
    const float4* in1 = in0 + (HW_/4);
    const float4* in2 = in1 + (HW_/4);
    const float4* lb  = (const float4*)labels + (size_t)(b * K_ + k0) * (HW_/4) + cbase;

    float acc[KT_][4];
#pragma unroll
    for (int kk = 0; kk < KT_; ++kk)
        acc[kk][0] = acc[kk][1] = acc[kk][2] = acc[kk][3] = 0.f;

#pragma unroll
    for (int it = 0; it < 4; ++it) {           // 16 rows * 256 cols / (256 thr * 4)
        const int idx = it * 256 + x;
        const float4 a0 = in0[idx];
        const float4 a1 = in1[idx];
        const float4 a2 = in2[idx];
        float4 lv[KT_];
#pragma unroll
        for (int kk = 0; kk < KT_; ++kk) lv[kk] = lb[kk * (HW_/4) + idx];
#pragma unroll
        for (int kk = 0; kk < KT_; ++kk) {
            const float4 l = lv[kk];
            acc[kk][0] += (l.x + l.y) + (l.z + l.w);
            acc[kk][1] += fmaf(l.w, a0.w, fmaf(l.z, a0.z, fmaf(l.y, a0.y, l.x * a0.x)));
            acc[kk][2] += fmaf(l.w, a1.w, fmaf(l.z, a1.z, fmaf(l.y, a1.y, l.x * a1.x)));
            acc[kk][3] += fmaf(l.w, a2.w, fmaf(l.z, a2.z, fmaf(l.y, a2.y, l.x * a2.x)));
        }
    }

#pragma unroll
    for (int kk = 0; kk < KT_; ++kk)
#pragma unroll
        for (int q = 0; q < 4; ++q)
            for (int o = 32; o > 0; o >>= 1)
                acc[kk][q] += __shfl_down(acc[kk][q], o);

    __shared__ float sred[4][KT_][4];
    const int widx = x >> 6, lane = x & 63;
    if (lane == 0)
#pragma unroll
        for (int kk = 0; kk < KT_; ++kk)
#pragma unroll
            for (int q = 0; q < 4; ++q) sred[widx][kk][q] = acc[kk][q];
    __syncthreads();
    if (x < KT_ * 4) {
        const int kk = x >> 2, q = x & 3;
        const float v = sred[0][kk][q] + sred[1][kk][q] + sred[2][kk][q] + sred[3][kk][q];
        ws[(chunk * 4 + q) * BK_ + b * K_ + k0 + kk] = v;
    }
}

// ---------------------------------------------------------------------------
// hblur4: 9-tap horizontal blur of a wave-wide row (64 lanes x float4).
// ---------------------------------------------------------------------------
__device__ __forceinline__ void hblur4(const float4 v, const int lane, float o[4]) {
    float u0 = __shfl_up(v.x, 1), u1 = __shfl_up(v.y, 1);
    float u2 = __shfl_up(v.z, 1), u3 = __shfl_up(v.w, 1);
    float d0 = __shfl_down(v.x, 1), d1 = __shfl_down(v.y, 1);
    float d2 = __shfl_down(v.z, 1), d3 = __shfl_down(v.w, 1);
    if (lane == 0)  { u0 = u1 = u2 = u3 = 0.f; }
    if (lane == 63) { d0 = d1 = d2 = d3 = 0.f; }
    o[0] = fmaf(G4T, u0 + d0, fmaf(G3T, u1 + v.w, fmaf(G2T, u2 + v.z, fmaf(G1T, u3 + v.y, v.x))));
    o[1] = fmaf(G4T, u1 + d1, fmaf(G3T, u2 + d0,  fmaf(G2T, u3 + v.w, fmaf(G1T, v.x + v.z, v.y))));
    o[2] = fmaf(G4T, u2 + d2, fmaf(G3T, u3 + d1,  fmaf(G2T, v.x + d0, fmaf(G1T, v.y + v.w, v.z))));
    o[3] = fmaf(G4T, u3 + d3, fmaf(G3T, v.x + d2, fmaf(G2T, v.y + d1, fmaf(G1T, v.z + d0,  v.w))));
}

// ---------------------------------------------------------------------------
// fused_k: wave-owns-row structure (no barriers/LDS in main loop) + explicit
// 2-deep register ping-pong prefetch (hides ~900cy HBM labels latency at
// 3 waves/SIMD) + 4-slot label ring (labels read ONCE per row).
// grid (4, K_, B_), block 256 = 4 waves = 4 strips of TH_=16 rows.
// ---------------------------------------------------------------------------
__global__ __launch_bounds__(256) void fused_k(const float* __restrict__ labels,
                                               const float* __restrict__ inputs,
                                               float* __restrict__ ws,
                                               float* __restrict__ out) {
    const int x = threadIdx.x;
    const int lane = x & 63;
    const int widx = x >> 6;
    const int sg = blockIdx.x;
    const int k = blockIdx.y;
    const int b = blockIdx.z;
    const int bk = b * K_ + k;
    const int r0 = (sg * 4 + widx) * TH_;

    // ---- class mean from stats partials (uniform per block) ----
    float s0 = 0.f, s1 = 0.f, s2 = 0.f, s3 = 0.f;
#pragma unroll
    for (int c = 0; c < SCH_; ++c) {
        const float* p = ws + c * 4 * BK_;
        s0 += p[bk]; s1 += p[BK_ + bk]; s2 += p[2*BK_ + bk]; s3 += p[3*BK_ + bk];
    }
    const float dn  = s0 + 1e-5f * (float)HW_;
    const float cm0 = s1 / dn, cm1 = s2 / dn, cm2 = s3 / dn;
    const float m2  = cm0*cm0 + cm1*cm1 + cm2*cm2;
    const float tc0 = 2.f*cm0, tc1 = 2.f*cm1, tc2 = 2.f*cm2;

    const float4* lb4  = (const float4*)labels + (size_t)bk * (HW_/4);
    const float4* in04 = (const float4*)inputs + (size_t)b * 3 * (HW_/4);
    const float4* in14 = in04 + (HW_/4);
    const float4* in24 = in14 + (HW_/4);

    auto wcalc = [&](const float4 a0, const float4 a1, const float4 a2,
                     const float4 l, float4& w4, float4& lw4) {
        const float d0 = fmaf(a0.x, a0.x - tc0, fmaf(a1.x, a1.x - tc1, fmaf(a2.x, a2.x - tc2, m2)));
        const float d1 = fmaf(a0.y, a0.y - tc0, fmaf(a1.y, a1.y - tc1, fmaf(a2.y, a2.y - tc2, m2)));
        const float d2 = fmaf(a0.z, a0.z - tc0, fmaf(a1.z, a1.z - tc1, fmaf(a2.z, a2.z - tc2, m2)));
        const float d3 = fmaf(a0.w, a0.w - tc0, fmaf(a1.w, a1.w - tc1, fmaf(a2.w, a2.w - tc2, m2)));
        w4.x = __expf(-d0*d0); w4.y = __expf(-d1*d1);
        w4.z = __expf(-d2*d2); w4.w = __expf(-d3*d3);
        lw4.x = l.x*w4.x; lw4.y = l.y*w4.y; lw4.z = l.z*w4.z; lw4.w = l.w*w4.w;
    };

    // ---- prologue: init H-blur ring (rows r0-4..r0+3) + label ring ----
    float rhw[8][4], rhlw[8][4];
    float rl[4][4];                 // labels rows r0..r0+3 (then ring)
#pragma unroll
    for (int i = 0; i < 8; ++i) {
        const int gr = r0 - 4 + i;
        float4 w4 = zero4(), lw4 = zero4(), l = zero4();
        if ((unsigned)gr < (unsigned)H_) {
            const int i4 = gr * (W_/4) + lane;
            l = lb4[i4];
            const float4 a0 = in04[i4];
            const float4 a1 = in14[i4];
            const float4 a2 = in24[i4];
            wcalc(a0, a1, a2, l, w4, lw4);
        }
        hblur4(w4,  lane, rhw[i]);
        hblur4(lw4, lane, rhlw[i]);
        if (i >= 4) { rl[i-4][0] = l.x; rl[i-4][1] = l.y; rl[i-4][2] = l.z; rl[i-4][3] = l.w; }
    }

    // ---- pre-issue loads for iterations 0 and 1 (rows r0+4, r0+5) ----
    float4 pl[2], pa0[2], pa1[2], pa2[2];
#pragma unroll
    for (int p = 0; p < 2; ++p) {
        const int gr = r0 + p + 4;
        if ((unsigned)gr < (unsigned)H_) {
            const int i4 = gr * (W_/4) + lane;
            pl[p] = lb4[i4]; pa0[p] = in04[i4]; pa1[p] = in14[i4]; pa2[p] = in24[i4];
        } else {
            pl[p] = zero4(); pa0[p] = zero4(); pa1[p] = zero4(); pa2[p] = zero4();
        }
    }

    float num = 0.f, den = 0.f;
#pragma unroll 1
    for (int ro = 0; ro < TH_ / 8; ++ro) {
#pragma unroll
        for (int u = 0; u < 8; ++u) {
            const int rr = ro * 8 + u;
            const int orow = r0 + rr;
            const int pb = u & 1;            // == rr&1
            // consume prefetched row orow+4
            const float4 l = pl[pb], a0 = pa0[pb], a1 = pa1[pb], a2 = pa2[pb];
            // issue loads for iteration rr+2 (row orow+6) into the freed slot
            {
                const int gr = orow + 6;
                if ((unsigned)gr < (unsigned)H_) {
                    const int i4 = gr * (W_/4) + lane;
                    pl[pb] = lb4[i4]; pa0[pb] = in04[i4]; pa1[pb] = in14[i4]; pa2[pb] = in24[i4];
                } else {
                    pl[pb] = zero4(); pa0[pb] = zero4(); pa1[pb] = zero4(); pa2[pb] = zero4();
                }
            }
            // weights for row orow+4
            float4 w4, lw4;
            wcalc(a0, a1, a2, l, w4, lw4);
            if (orow + 4 >= H_) { w4 = zero4(); lw4 = zero4(); }
            float cw[4], clw[4];
            hblur4(w4,  lane, cw);
            hblur4(lw4, lane, clw);
            // labels at output row from the 4-slot ring, then recycle slot
            const int ls = u & 3;            // == rr&3
            const float lca[4] = {rl[ls][0], rl[ls][1], rl[ls][2], rl[ls][3]};
            rl[ls][0] = l.x; rl[ls][1] = l.y; rl[ls][2] = l.z; rl[ls][3] = l.w;
            // vertical 9-tap (symmetric pairs), fused into num/den
            const int s0i = u, s1i = (u+1)&7, s2i = (u+2)&7, s3i = (u+3)&7;
            const int s4i = (u+4)&7, s5i = (u+5)&7, s6i = (u+6)&7, s7i = (u+7)&7;
#pragma unroll
            for (int c = 0; c < 4; ++c) {
                const float vw = fmaf(G4T, rhw[s0i][c] + cw[c],
                                 fmaf(G3T, rhw[s1i][c] + rhw[s7i][c],
                                 fmaf(G2T, rhw[s2i][c] + rhw[s6i][c],
                                 fmaf(G1T, rhw[s3i][c] + rhw[s5i][c], rhw[s4i][c]))));
                const float vl = fmaf(G4T, rhlw[s0i][c] + clw[c],
                                 fmaf(G3T, rhlw[s1i][c] + rhlw[s7i][c],
                                 fmaf(G2T, rhlw[s2i][c] + rhlw[s6i][c],
                                 fmaf(G1T, rhlw[s3i][c] + rhlw[s5i][c], rhlw[s4i][c]))));
                num = fmaf(lca[c], vl, num);
                den = fmaf(lca[c], vw, den);
            }
#pragma unroll
            for (int c = 0; c < 4; ++c) { rhw[u][c] = cw[c]; rhlw[u][c] = clw[c]; }
        }
    }

    // ---- block reduce + last-block finalize ----
    for (int o = 32; o > 0; o >>= 1) { num += __shfl_down(num, o); den += __shfl_down(den, o); }
    __shared__ float rb[4][2];
    __shared__ unsigned sdone;
    if (lane == 0) { rb[widx][0] = num; rb[widx][1] = den; }
    __syncthreads();
    if (x == 0) {
        const float fn = rb[0][0] + rb[1][0] + rb[2][0] + rb[3][0];
        const float fd = rb[0][1] + rb[1][1] + rb[2][1] + rb[3][1];
        float2* nd2 = (float2*)(ws + WS_ND_);
        nd2[k * 64 + b * 4 + sg] = make_float2(fn, fd);
        __threadfence();
        sdone = atomicAdd((unsigned*)(ws + WS_CNT_), 1u);
    }
    __syncthreads();
    if (sdone == (unsigned)(NBLK_FUSED_ - 1)) {
        __threadfence();
        if (x < 64) {
            float term = 0.f;
            if (x < K_) {
                const float2* nd2 = (const float2*)(ws + WS_ND_);
                float ns = 0.f, ds = 0.f;
                for (int i = 0; i < 64; ++i) {
                    const float2 v = nd2[x * 64 + i];
                    ns += v.x; ds += v.y;
                }
                term = fabsf(ns / (ds + 1e-6f));
            }
            for (int o = 32; o > 0; o >>= 1) term += __shfl_down(term, o);
            if (x == 0) out[0] = (float)K_ - term;
        }
    }
}

extern "C" void kernel_launch(void* const* d_in, const int* in_sizes, int n_in,
                              void* d_out, int out_size, void* d_ws, size_t ws_size,
                              hipStream_t stream) {
    const float* labels = (const float*)d_in[0];
    const float* inputs = (const float*)d_in[1];
    float* ws = (float*)d_ws;   // needs WS_CNT_+1 floats ~= 92 KB

    stats_k<<<dim3(SCH_, K_ / KT_, B_), 256, 0, stream>>>(labels, inputs, ws);
    fused_k<<<dim3(4, K_, B_), 256, 0, stream>>>(labels, inputs, ws, (float*)d_out);
}

// Round 5
// 207.961 us; speedup vs baseline: 1.2240x; 1.2240x over previous
//
#include <hip/hip_runtime.h>

#define B_ 16
#define K_ 20
#define H_ 256
#define W_ 256
#define HW_ (H_*W_)
#define BK_ (B_*K_)
#define TH_ 16          // output rows per WAVE strip (16 strips/image)
#define KT_ 5           // classes per stats block
#define SCH_ 16         // stats row-chunks (16 rows each) -> 1024 blocks
#define NBLK_FUSED_ (4*K_*B_)   // fused grid = 1280 blocks

// ws layout (floats): statsP [SCH_][4][BK_] | ndP [NBLK][2] | cnt  (~92 KB)
#define WS_ND_   (SCH_*4*BK_)
#define WS_CNT_  (WS_ND_ + 2*NBLK_FUSED_)

// Gaussian taps exp(-d^2/50), d=1..4 (symmetric: 4 distinct + center 1.0)
#define G1T 0.980198673f
#define G2T 0.923116346f
#define G3T 0.835270211f
#define G4T 0.726149037f

__device__ __forceinline__ float4 zero4() { return make_float4(0.f, 0.f, 0.f, 0.f); }
__device__ __forceinline__ float rfl(float v) {   // force value into SGPR
    return __int_as_float(__builtin_amdgcn_readfirstlane(__float_as_int(v)));
}

// ---------------------------------------------------------------------------
// stats_k: per-(b,k) sums of labels and labels*inputs_c as per-chunk partials.
// grid (SCH_=16, K_/KT_=4, B_=16) = 1024 blocks. Batched float4 loads.
// ---------------------------------------------------------------------------
__global__ __launch_bounds__(256) void stats_k(const float* __restrict__ labels,
                                               const float* __restrict__ inputs,
                                               float* __restrict__ ws) {
    const int x = threadIdx.x;
    const int chunk = blockIdx.x;
    const int kt = blockIdx.y;
    const int b  = blockIdx.z;
    const int k0 = kt * KT_;
    if (chunk == 0 && kt == 0 && b == 0 && x == 0)
        ((unsigned*)(ws + WS_CNT_))[0] = 0u;   // reset fused completion counter

    const int cbase = chunk * (16 * W_ / 4);
    const float4* in0 = (const float4*)inputs + (size_t)b * 3 * (HW_/4) + cbase;
    const float4* in1 = in0 + (HW_/4);
    const float4* in2 = in1 + (HW_/4);
    const float4* lb  = (const float4*)labels + (size_t)(b * K_ + k0) * (HW_/4) + cbase;

    float acc[KT_][4];
#pragma unroll
    for (int kk = 0; kk < KT_; ++kk)
        acc[kk][0] = acc[kk][1] = acc[kk][2] = acc[kk][3] = 0.f;

#pragma unroll
    for (int it = 0; it < 4; ++it) {
        const int idx = it * 256 + x;
        const float4 a0 = in0[idx];
        const float4 a1 = in1[idx];
        const float4 a2 = in2[idx];
        float4 lv[KT_];
#pragma unroll
        for (int kk = 0; kk < KT_; ++kk) lv[kk] = lb[kk * (HW_/4) + idx];
#pragma unroll
        for (int kk = 0; kk < KT_; ++kk) {
            const float4 l = lv[kk];
            acc[kk][0] += (l.x + l.y) + (l.z + l.w);
            acc[kk][1] += fmaf(l.w, a0.w, fmaf(l.z, a0.z, fmaf(l.y, a0.y, l.x * a0.x)));
            acc[kk][2] += fmaf(l.w, a1.w, fmaf(l.z, a1.z, fmaf(l.y, a1.y, l.x * a1.x)));
            acc[kk][3] += fmaf(l.w, a2.w, fmaf(l.z, a2.z, fmaf(l.y, a2.y, l.x * a2.x)));
        }
    }

#pragma unroll
    for (int kk = 0; kk < KT_; ++kk)
#pragma unroll
        for (int q = 0; q < 4; ++q)
            for (int o = 32; o > 0; o >>= 1)
                acc[kk][q] += __shfl_down(acc[kk][q], o);

    __shared__ float sred[4][KT_][4];
    const int widx = x >> 6, lane = x & 63;
    if (lane == 0)
#pragma unroll
        for (int kk = 0; kk < KT_; ++kk)
#pragma unroll
            for (int q = 0; q < 4; ++q) sred[widx][kk][q] = acc[kk][q];
    __syncthreads();
    if (x < KT_ * 4) {
        const int kk = x >> 2, q = x & 3;
        const float v = sred[0][kk][q] + sred[1][kk][q] + sred[2][kk][q] + sred[3][kk][q];
        ws[(chunk * 4 + q) * BK_ + b * K_ + k0 + kk] = v;
    }
}

// ---------------------------------------------------------------------------
// hblur4: 9-tap horizontal blur of a wave-wide row (64 lanes x float4).
// ---------------------------------------------------------------------------
__device__ __forceinline__ void hblur4(const float4 v, const int lane, float o[4]) {
    float u0 = __shfl_up(v.x, 1), u1 = __shfl_up(v.y, 1);
    float u2 = __shfl_up(v.z, 1), u3 = __shfl_up(v.w, 1);
    float d0 = __shfl_down(v.x, 1), d1 = __shfl_down(v.y, 1);
    float d2 = __shfl_down(v.z, 1), d3 = __shfl_down(v.w, 1);
    if (lane == 0)  { u0 = u1 = u2 = u3 = 0.f; }   // image left edge (zero pad)
    if (lane == 63) { d0 = d1 = d2 = d3 = 0.f; }   // image right edge
    o[0] = fmaf(G4T, u0 + d0, fmaf(G3T, u1 + v.w, fmaf(G2T, u2 + v.z, fmaf(G1T, u3 + v.y, v.x))));
    o[1] = fmaf(G4T, u1 + d1, fmaf(G3T, u2 + d0,  fmaf(G2T, u3 + v.w, fmaf(G1T, v.x + v.z, v.y))));
    o[2] = fmaf(G4T, u2 + d2, fmaf(G3T, u3 + d1,  fmaf(G2T, v.x + d0, fmaf(G1T, v.y + v.w, v.z))));
    o[3] = fmaf(G4T, u3 + d3, fmaf(G3T, v.x + d2, fmaf(G2T, v.y + d1, fmaf(G1T, v.z + d0,  v.w))));
}

// ---------------------------------------------------------------------------
// fused_k, ADJOINT form: since the blur G is symmetric with zero padding,
//   num = sum l*blur(l*w) = sum (l*w)*blur(l),  den = sum l*blur(w) = sum w*blur(l)
// so only LABELS are blurred (one field instead of two): ring halves to
// rhl[8][4], one hblur/row, one vertical blur, weights evaluated only at
// in-range output rows. t = w*blur(l); den += t; num += l*t.
// Wave owns a full row (64 lanes x float4): no barriers/LDS in main loop.
// 1-deep load pipeline (labels row+5, inputs row+1). Uniforms in SGPRs.
// grid: 1280 blocks 1D with bijective XCD-chunk swizzle (1280 % 8 == 0).
// ---------------------------------------------------------------------------
__global__ __launch_bounds__(256) void fused_k(const float* __restrict__ labels,
                                               const float* __restrict__ inputs,
                                               float* __restrict__ ws,
                                               float* __restrict__ out) {
    const int x = threadIdx.x;
    const int lane = x & 63;
    const int widx = x >> 6;
    // XCD-chunked swizzle: 160 contiguous work-items per XCD
    const int bid = blockIdx.x;
    const int swz = (bid & 7) * (NBLK_FUSED_ / 8) + (bid >> 3);
    const int b   = swz / (4 * K_);
    const int rem = swz - b * (4 * K_);
    const int k   = rem >> 2;
    const int sg  = rem & 3;
    const int bk  = b * K_ + k;
    const int r0  = (sg * 4 + widx) * TH_;

    // ---- class mean from stats partials (uniform -> SGPRs) ----
    float s0 = 0.f, s1 = 0.f, s2 = 0.f, s3 = 0.f;
#pragma unroll
    for (int c = 0; c < SCH_; ++c) {
        const float* p = ws + c * 4 * BK_;
        s0 += p[bk]; s1 += p[BK_ + bk]; s2 += p[2*BK_ + bk]; s3 += p[3*BK_ + bk];
    }
    const float dnv = s0 + 1e-5f * (float)HW_;
    const float c0 = s1 / dnv, c1 = s2 / dnv, c2 = s3 / dnv;
    const float tc0 = rfl(2.f * c0), tc1 = rfl(2.f * c1), tc2 = rfl(2.f * c2);
    const float m2v = rfl(c0*c0 + c1*c1 + c2*c2);

    const float4* lb4  = (const float4*)labels + (size_t)bk * (HW_/4);
    const float4* in04 = (const float4*)inputs + (size_t)b * 3 * (HW_/4);
    const float4* in14 = in04 + (HW_/4);
    const float4* in24 = in14 + (HW_/4);

    // ---- ring init: h-blurred LABEL rows r0-4 .. r0+3 (slot i = row r0-4+i)
    float rhl[8][4];
#pragma unroll
    for (int i = 0; i < 8; ++i) {
        const int gr = r0 - 4 + i;
        float4 l = zero4();
        if ((unsigned)gr < (unsigned)H_) l = lb4[gr * (W_/4) + lane];
        hblur4(l, lane, rhl[i]);
    }

    // ---- pipeline prologue: iter-0 data ----
    float4 hl = lb4[(r0 + 4) * (W_/4) + lane];     // labels row r0+4 (<=244, in range)
    float4 h0 = in04[r0 * (W_/4) + lane];
    float4 h1 = in14[r0 * (W_/4) + lane];
    float4 h2 = in24[r0 * (W_/4) + lane];

    float num = 0.f, den = 0.f;
#pragma unroll 1
    for (int ro = 0; ro < TH_ / 8; ++ro) {
#pragma unroll
        for (int u = 0; u < 8; ++u) {
            const int orow = r0 + ro * 8 + u;      // output row, always < H_
            // ---- issue next-iter loads (consumed next iteration) ----
            float4 nl = zero4();
            if (orow + 5 < H_) nl = lb4[(orow + 5) * (W_/4) + lane];   // uniform branch
            const int nir = (orow + 1 < H_) ? orow + 1 : H_ - 1;       // clamp (value unused at tail)
            const float4 n0 = in04[nir * (W_/4) + lane];
            const float4 n1 = in14[nir * (W_/4) + lane];
            const float4 n2 = in24[nir * (W_/4) + lane];
            const float4 lo4 = lb4[orow * (W_/4) + lane];              // labels at output row (cache hit)
            // ---- vertical partial from ring (8 of 9 taps) ----
            const int s0i = u, s1i = (u+1)&7, s2i = (u+2)&7, s3i = (u+3)&7;
            const int s4i = (u+4)&7, s5i = (u+5)&7, s6i = (u+6)&7, s7i = (u+7)&7;
            float part[4];
#pragma unroll
            for (int c = 0; c < 4; ++c)
                part[c] = fmaf(G3T, rhl[s1i][c] + rhl[s7i][c],
                          fmaf(G2T, rhl[s2i][c] + rhl[s6i][c],
                          fmaf(G1T, rhl[s3i][c] + rhl[s5i][c], rhl[s4i][c])));
            // ---- weights at output row from held inputs ----
            const float d0 = fmaf(h0.x, h0.x - tc0, fmaf(h1.x, h1.x - tc1, fmaf(h2.x, h2.x - tc2, m2v)));
            const float d1 = fmaf(h0.y, h0.y - tc0, fmaf(h1.y, h1.y - tc1, fmaf(h2.y, h2.y - tc2, m2v)));
            const float d2 = fmaf(h0.z, h0.z - tc0, fmaf(h1.z, h1.z - tc1, fmaf(h2.z, h2.z - tc2, m2v)));
            const float d3 = fmaf(h0.w, h0.w - tc0, fmaf(h1.w, h1.w - tc1, fmaf(h2.w, h2.w - tc2, m2v)));
            const float wv[4] = {__expf(-d0*d0), __expf(-d1*d1), __expf(-d2*d2), __expf(-d3*d3)};
            // ---- h-blur held labels (row orow+4) ----
            float cur[4];
            hblur4(hl, lane, cur);
            // ---- combine: bl = blur(l); t = w*bl; den += t; num += l*t ----
            const float loa[4] = {lo4.x, lo4.y, lo4.z, lo4.w};
#pragma unroll
            for (int c = 0; c < 4; ++c) {
                const float bl = fmaf(G4T, rhl[s0i][c] + cur[c], part[c]);
                const float t  = wv[c] * bl;
                den += t;
                num = fmaf(loa[c], t, num);
            }
            // ---- ring replace oldest (row orow-4) with row orow+4 ----
#pragma unroll
            for (int c = 0; c < 4; ++c) rhl[u][c] = cur[c];
            // ---- advance pipeline (renamed by unroll, no movs) ----
            hl = nl; h0 = n0; h1 = n1; h2 = n2;
        }
    }

    // ---- block reduce + last-block finalize ----
    for (int o = 32; o > 0; o >>= 1) { num += __shfl_down(num, o); den += __shfl_down(den, o); }
    __shared__ float rb[4][2];
    __shared__ unsigned sdone;
    if (lane == 0) { rb[widx][0] = num; rb[widx][1] = den; }
    __syncthreads();
    if (x == 0) {
        const float fn = rb[0][0] + rb[1][0] + rb[2][0] + rb[3][0];
        const float fd = rb[0][1] + rb[1][1] + rb[2][1] + rb[3][1];
        float2* nd2 = (float2*)(ws + WS_ND_);
        nd2[k * 64 + b * 4 + sg] = make_float2(fn, fd);
        __threadfence();
        sdone = atomicAdd((unsigned*)(ws + WS_CNT_), 1u);
    }
    __syncthreads();
    if (sdone == (unsigned)(NBLK_FUSED_ - 1)) {
        __threadfence();
        if (x < 64) {
            float term = 0.f;
            if (x < K_) {
                const float2* nd2 = (const float2*)(ws + WS_ND_);
                float ns = 0.f, ds = 0.f;
                for (int i = 0; i < 64; ++i) {
                    const float2 v = nd2[x * 64 + i];
                    ns += v.x; ds += v.y;
                }
                term = fabsf(ns / (ds + 1e-6f));
            }
            for (int o = 32; o > 0; o >>= 1) term += __shfl_down(term, o);
            if (x == 0) out[0] = (float)K_ - term;
        }
    }
}

extern "C" void kernel_launch(void* const* d_in, const int* in_sizes, int n_in,
                              void* d_out, int out_size, void* d_ws, size_t ws_size,
                              hipStream_t stream) {
    const float* labels = (const float*)d_in[0];
    const float* inputs = (const float*)d_in[1];
    float* ws = (float*)d_ws;   // needs WS_CNT_+1 floats ~= 92 KB

    stats_k<<<dim3(SCH_, K_ / KT_, B_), 256, 0, stream>>>(labels, inputs, ws);
    fused_k<<<NBLK_FUSED_, 256, 0, stream>>>(labels, inputs, ws, (float*)d_out);
}

// Round 6
// 197.601 us; speedup vs baseline: 1.2881x; 1.0524x over previous
//
#include <hip/hip_runtime.h>

#define B_ 16
#define K_ 20
#define H_ 256
#define W_ 256
#define HW_ (H_*W_)
#define BK_ (B_*K_)
#define TH_ 64          // rows per BLOCK strip (4 strips/image), round-0 geometry
#define KT_ 5           // classes per stats block
#define SCH_ 16         // stats row-chunks (16 rows each) -> 1024 blocks
#define NBLK_FUSED_ (4*K_*B_)   // fused grid = 1280 blocks

// ws layout (floats): statsP [SCH_][4][BK_] | ndP [NBLK][2] | cnt  (~92 KB)
#define WS_ND_   (SCH_*4*BK_)
#define WS_CNT_  (WS_ND_ + 2*NBLK_FUSED_)

// Gaussian taps exp(-d^2/50), d=1..4 (symmetric: 4 distinct + center 1.0)
#define G1T 0.980198673f
#define G2T 0.923116346f
#define G3T 0.835270211f
#define G4T 0.726149037f

__device__ __forceinline__ float rfl(float v) {   // force value into SGPR
    return __int_as_float(__builtin_amdgcn_readfirstlane(__float_as_int(v)));
}

// ---------------------------------------------------------------------------
// stats_k: per-(b,k) sums of labels and labels*inputs_c as per-chunk partials.
// grid (SCH_=16, K_/KT_=4, B_=16) = 1024 blocks. Batched float4 loads.
// ---------------------------------------------------------------------------
__global__ __launch_bounds__(256) void stats_k(const float* __restrict__ labels,
                                               const float* __restrict__ inputs,
                                               float* __restrict__ ws) {
    const int x = threadIdx.x;
    const int chunk = blockIdx.x;
    const int kt = blockIdx.y;
    const int b  = blockIdx.z;
    const int k0 = kt * KT_;
    if (chunk == 0 && kt == 0 && b == 0 && x == 0)
        ((unsigned*)(ws + WS_CNT_))[0] = 0u;   // reset fused completion counter

    const int cbase = chunk * (16 * W_ / 4);
    const float4* in0 = (const float4*)inputs + (size_t)b * 3 * (HW_/4) + cbase;
    const float4* in1 = in0 + (HW_/4);
    const float4* in2 = in1 + (HW_/4);
    const float4* lb  = (const float4*)labels + (size_t)(b * K_ + k0) * (HW_/4) + cbase;

    float acc[KT_][4];
#pragma unroll
    for (int kk = 0; kk < KT_; ++kk)
        acc[kk][0] = acc[kk][1] = acc[kk][2] = acc[kk][3] = 0.f;

#pragma unroll
    for (int it = 0; it < 4; ++it) {
        const int idx = it * 256 + x;
        const float4 a0 = in0[idx];
        const float4 a1 = in1[idx];
        const float4 a2 = in2[idx];
        float4 lv[KT_];
#pragma unroll
        for (int kk = 0; kk < KT_; ++kk) lv[kk] = lb[kk * (HW_/4) + idx];
#pragma unroll
        for (int kk = 0; kk < KT_; ++kk) {
            const float4 l = lv[kk];
            acc[kk][0] += (l.x + l.y) + (l.z + l.w);
            acc[kk][1] += fmaf(l.w, a0.w, fmaf(l.z, a0.z, fmaf(l.y, a0.y, l.x * a0.x)));
            acc[kk][2] += fmaf(l.w, a1.w, fmaf(l.z, a1.z, fmaf(l.y, a1.y, l.x * a1.x)));
            acc[kk][3] += fmaf(l.w, a2.w, fmaf(l.z, a2.z, fmaf(l.y, a2.y, l.x * a2.x)));
        }
    }

#pragma unroll
    for (int kk = 0; kk < KT_; ++kk)
#pragma unroll
        for (int q = 0; q < 4; ++q)
            for (int o = 32; o > 0; o >>= 1)
                acc[kk][q] += __shfl_down(acc[kk][q], o);

    __shared__ float sred[4][KT_][4];
    const int widx = x >> 6, lane = x & 63;
    if (lane == 0)
#pragma unroll
        for (int kk = 0; kk < KT_; ++kk)
#pragma unroll
            for (int q = 0; q < 4; ++q) sred[widx][kk][q] = acc[kk][q];
    __syncthreads();
    if (x < KT_ * 4) {
        const int kk = x >> 2, q = x & 3;
        const float v = sred[0][kk][q] + sred[1][kk][q] + sred[2][kk][q] + sred[3][kk][q];
        ws[(chunk * 4 + q) * BK_ + b * K_ + k0 + kk] = v;
    }
}

// ---------------------------------------------------------------------------
// fused_k, scalar-column ADJOINT form.
//   num = sum (l*w)*blur(l),  den = sum w*blur(l)   (G symmetric, zero-pad)
// One thread per column (256 threads = whole row). Raw-label mod-8 register
// ring feeds the vertical 9-tap AND provides the output-row label for free.
// One LDS round-trip + ONE barrier per row (double-buffered row, stride-1
// accesses -> conflict-free). Weights evaluated only at in-range output rows.
// 1-row-deep scalar prefetch (4 dword loads/row, consumed next iteration).
// Tiny state (~45 VGPR) -> all 1280 blocks co-resident, latency hidden by TLP
// (round-0 empirically hit 65% VALUBusy with this structure at 32 VGPR).
// grid: 1280 blocks 1D, bijective XCD-chunk swizzle (1280 % 8 == 0).
// ---------------------------------------------------------------------------
__global__ __launch_bounds__(256) void fused_k(const float* __restrict__ labels,
                                               const float* __restrict__ inputs,
                                               float* __restrict__ ws,
                                               float* __restrict__ out) {
    const int x = threadIdx.x;            // column
    const int bid = blockIdx.x;
    const int swz = (bid & 7) * (NBLK_FUSED_ / 8) + (bid >> 3);
    const int b   = swz / (4 * K_);
    const int rem = swz - b * (4 * K_);
    const int k   = rem >> 2;
    const int sg  = rem & 3;
    const int bk  = b * K_ + k;
    const int r0  = sg * TH_;

    // ---- class mean from stats partials (uniform -> SGPRs) ----
    float s0 = 0.f, s1 = 0.f, s2 = 0.f, s3 = 0.f;
#pragma unroll
    for (int c = 0; c < SCH_; ++c) {
        const float* p = ws + c * 4 * BK_;
        s0 += p[bk]; s1 += p[BK_ + bk]; s2 += p[2*BK_ + bk]; s3 += p[3*BK_ + bk];
    }
    const float dnv = s0 + 1e-5f * (float)HW_;
    const float c0 = s1 / dnv, c1 = s2 / dnv, c2 = s3 / dnv;
    const float tc0 = rfl(2.f * c0), tc1 = rfl(2.f * c1), tc2 = rfl(2.f * c2);
    const float m2v = rfl(c0*c0 + c1*c1 + c2*c2);

    const float* lb  = labels + (size_t)bk * HW_;
    const float* i0p = inputs + (size_t)b * 3 * HW_;
    const float* i1p = i0p + HW_;
    const float* i2p = i1p + HW_;

    __shared__ float sv[2][W_ + 8];       // zero pads [0..3], [W+4..W+7]
    if (x < 4) {
        sv[0][x] = 0.f; sv[0][W_ + 4 + x] = 0.f;
        sv[1][x] = 0.f; sv[1][W_ + 4 + x] = 0.f;
    }

    // raw-label ring: slot i holds row r0-4+i (rows r0+3 <= 195 always < H)
    float rl[8];
#pragma unroll
    for (int i = 0; i < 8; ++i) {
        const int gr = r0 - 4 + i;
        rl[i] = (gr >= 0) ? lb[gr * W_ + x] : 0.f;
    }
    // pipeline prologue: labels row r0+4 (<=196, in range), inputs row r0
    float hl  = lb[(r0 + 4) * W_ + x];
    float hi0 = i0p[r0 * W_ + x];
    float hi1 = i1p[r0 * W_ + x];
    float hi2 = i2p[r0 * W_ + x];

    __syncthreads();                      // pads visible before first h-pass

    float num = 0.f, den = 0.f;
#pragma unroll 1
    for (int ro = 0; ro < TH_ / 8; ++ro) {
#pragma unroll
        for (int u = 0; u < 8; ++u) {
            const int orow = r0 + ro * 8 + u;          // always < H_
            // ---- issue next-row loads (consumed next iteration) ----
            float nl = 0.f;
            if (orow + 5 < H_) nl = lb[(orow + 5) * W_ + x];   // uniform branch
            const int nir = (orow + 1 < H_) ? orow + 1 : H_ - 1;
            const float ni0 = i0p[nir * W_ + x];
            const float ni1 = i1p[nir * W_ + x];
            const float ni2 = i2p[nir * W_ + x];
            // ---- vertical 9-tap on raw labels (ring + incoming) ----
            const float vbl = fmaf(G4T, rl[u] + hl,
                              fmaf(G3T, rl[(u+1)&7] + rl[(u+7)&7],
                              fmaf(G2T, rl[(u+2)&7] + rl[(u+6)&7],
                              fmaf(G1T, rl[(u+3)&7] + rl[(u+5)&7], rl[(u+4)&7]))));
            // ---- horizontal 9-tap via LDS row (double-buffered, 1 barrier) --
            const int bf = u & 1;
            sv[bf][4 + x] = vbl;
            __syncthreads();
            const float* s = &sv[bf][x];
            const float bl = fmaf(G4T, s[0] + s[8],
                             fmaf(G3T, s[1] + s[7],
                             fmaf(G2T, s[2] + s[6],
                             fmaf(G1T, s[3] + s[5], s[4]))));
            // ---- weight at output row from held inputs ----
            const float d = fmaf(hi0, hi0 - tc0,
                            fmaf(hi1, hi1 - tc1,
                            fmaf(hi2, hi2 - tc2, m2v)));
            const float w = __expf(-d * d);            // SIGMA_2 = 1
            const float t = w * bl;
            den += t;
            num = fmaf(rl[(u + 4) & 7], t, num);       // raw label at orow
            // ---- ring replace oldest (orow-4) with orow+4; advance pipe ----
            rl[u] = hl;
            hl = nl; hi0 = ni0; hi1 = ni1; hi2 = ni2;
        }
    }

    // ---- block reduce + last-block finalize ----
    const int widx = x >> 6, lane = x & 63;
    for (int o = 32; o > 0; o >>= 1) { num += __shfl_down(num, o); den += __shfl_down(den, o); }
    __shared__ float rb[4][2];
    __shared__ unsigned sdone;
    __syncthreads();
    if (lane == 0) { rb[widx][0] = num; rb[widx][1] = den; }
    __syncthreads();
    if (x == 0) {
        const float fn = rb[0][0] + rb[1][0] + rb[2][0] + rb[3][0];
        const float fd = rb[0][1] + rb[1][1] + rb[2][1] + rb[3][1];
        float2* nd2 = (float2*)(ws + WS_ND_);
        nd2[k * 64 + b * 4 + sg] = make_float2(fn, fd);
        __threadfence();
        sdone = atomicAdd((unsigned*)(ws + WS_CNT_), 1u);
    }
    __syncthreads();
    if (sdone == (unsigned)(NBLK_FUSED_ - 1)) {
        __threadfence();
        if (x < 64) {
            float term = 0.f;
            if (x < K_) {
                const float2* nd2 = (const float2*)(ws + WS_ND_);
                float ns = 0.f, ds = 0.f;
                for (int i = 0; i < 64; ++i) {
                    const float2 v = nd2[x * 64 + i];
                    ns += v.x; ds += v.y;
                }
                term = fabsf(ns / (ds + 1e-6f));
            }
            for (int o = 32; o > 0; o >>= 1) term += __shfl_down(term, o);
            if (x == 0) out[0] = (float)K_ - term;
        }
    }
}

extern "C" void kernel_launch(void* const* d_in, const int* in_sizes, int n_in,
                              void* d_out, int out_size, void* d_ws, size_t ws_size,
                              hipStream_t stream) {
    const float* labels = (const float*)d_in[0];
    const float* inputs = (const float*)d_in[1];
    float* ws = (float*)d_ws;   // needs WS_CNT_+1 floats ~= 92 KB

    stats_k<<<dim3(SCH_, K_ / KT_, B_), 256, 0, stream>>>(labels, inputs, ws);
    fused_k<<<NBLK_FUSED_, 256, 0, stream>>>(labels, inputs, ws, (float*)d_out);
}

// Round 7
// 197.209 us; speedup vs baseline: 1.2907x; 1.0020x over previous
//
#include <hip/hip_runtime.h>

#define B_ 16
#define K_ 20
#define H_ 256
#define W_ 256
#define HW_ (H_*W_)
#define BK_ (B_*K_)
#define TH_ 64          // rows per BLOCK strip (4 strips/image)
#define BATCH_ 8        // rows per barrier phase
#define KT_ 5           // classes per stats block
#define SCH_ 16         // stats row-chunks (16 rows each) -> 1024 blocks
#define NBLK_FUSED_ (4*K_*B_)   // fused grid = 1280 blocks

// ws layout (floats): statsP [SCH_][4][BK_] | ndP [NBLK][2] | cnt  (~92 KB)
#define WS_ND_   (SCH_*4*BK_)
#define WS_CNT_  (WS_ND_ + 2*NBLK_FUSED_)

// Gaussian taps exp(-d^2/50), d=1..4 (symmetric: 4 distinct + center 1.0)
#define G1T 0.980198673f
#define G2T 0.923116346f
#define G3T 0.835270211f
#define G4T 0.726149037f

__device__ __forceinline__ float rfl(float v) {   // force value into SGPR
    return __int_as_float(__builtin_amdgcn_readfirstlane(__float_as_int(v)));
}

// ---------------------------------------------------------------------------
// stats_k: per-(b,k) sums of labels and labels*inputs_c as per-chunk partials.
// grid (SCH_=16, K_/KT_=4, B_=16) = 1024 blocks. Batched float4 loads.
// ---------------------------------------------------------------------------
__global__ __launch_bounds__(256) void stats_k(const float* __restrict__ labels,
                                               const float* __restrict__ inputs,
                                               float* __restrict__ ws) {
    const int x = threadIdx.x;
    const int chunk = blockIdx.x;
    const int kt = blockIdx.y;
    const int b  = blockIdx.z;
    const int k0 = kt * KT_;
    if (chunk == 0 && kt == 0 && b == 0 && x == 0)
        ((unsigned*)(ws + WS_CNT_))[0] = 0u;   // reset fused completion counter

    const int cbase = chunk * (16 * W_ / 4);
    const float4* in0 = (const float4*)inputs + (size_t)b * 3 * (HW_/4) + cbase;
    const float4* in1 = in0 + (HW_/4);
    const float4* in2 = in1 + (HW_/4);
    const float4* lb  = (const float4*)labels + (size_t)(b * K_ + k0) * (HW_/4) + cbase;

    float acc[KT_][4];
#pragma unroll
    for (int kk = 0; kk < KT_; ++kk)
        acc[kk][0] = acc[kk][1] = acc[kk][2] = acc[kk][3] = 0.f;

#pragma unroll
    for (int it = 0; it < 4; ++it) {
        const int idx = it * 256 + x;
        const float4 a0 = in0[idx];
        const float4 a1 = in1[idx];
        const float4 a2 = in2[idx];
        float4 lv[KT_];
#pragma unroll
        for (int kk = 0; kk < KT_; ++kk) lv[kk] = lb[kk * (HW_/4) + idx];
#pragma unroll
        for (int kk = 0; kk < KT_; ++kk) {
            const float4 l = lv[kk];
            acc[kk][0] += (l.x + l.y) + (l.z + l.w);
            acc[kk][1] += fmaf(l.w, a0.w, fmaf(l.z, a0.z, fmaf(l.y, a0.y, l.x * a0.x)));
            acc[kk][2] += fmaf(l.w, a1.w, fmaf(l.z, a1.z, fmaf(l.y, a1.y, l.x * a1.x)));
            acc[kk][3] += fmaf(l.w, a2.w, fmaf(l.z, a2.z, fmaf(l.y, a2.y, l.x * a2.x)));
        }
    }

#pragma unroll
    for (int kk = 0; kk < KT_; ++kk)
#pragma unroll
        for (int q = 0; q < 4; ++q)
            for (int o = 32; o > 0; o >>= 1)
                acc[kk][q] += __shfl_down(acc[kk][q], o);

    __shared__ float sred[4][KT_][4];
    const int widx = x >> 6, lane = x & 63;
    if (lane == 0)
#pragma unroll
        for (int kk = 0; kk < KT_; ++kk)
#pragma unroll
            for (int q = 0; q < 4; ++q) sred[widx][kk][q] = acc[kk][q];
    __syncthreads();
    if (x < KT_ * 4) {
        const int kk = x >> 2, q = x & 3;
        const float v = sred[0][kk][q] + sred[1][kk][q] + sred[2][kk][q] + sred[3][kk][q];
        ws[(chunk * 4 + q) * BK_ + b * K_ + k0 + kk] = v;
    }
}

// ---------------------------------------------------------------------------
// fused_k, scalar-column ADJOINT form, 8-ROW BATCHED barrier phases.
//   num = sum (l*w)*blur(l),  den = sum w*blur(l)   (G symmetric, zero-pad)
// Per batch of 8 output rows: vertical 9-tap needs rows R-4..R+11 which is
// EXACTLY ring[8] (R-4..R+3) + PL[8] (R+4..R+11), all in registers -> no
// loads on the vertical path. One barrier per batch (64 -> 9 drains/block);
// next-batch loads (8 labels + 24 inputs) are issued at batch start and have
// a full batch of compute x 5 waves/SIMD before their drain point.
// LDS: double-buffered 8-row h-blur staging, stride-1 (conflict-free).
// CAT(m): concat view, index 0 = row R-4 (static after unroll).
// grid: 1280 blocks 1D, bijective XCD-chunk swizzle (1280 % 8 == 0).
// ---------------------------------------------------------------------------
#define CAT(m) (((m) < 8) ? ring[(m)&7] : PL[(m)&7])

__global__ __launch_bounds__(256) void fused_k(const float* __restrict__ labels,
                                               const float* __restrict__ inputs,
                                               float* __restrict__ ws,
                                               float* __restrict__ out) {
    const int x = threadIdx.x;            // column
    const int bid = blockIdx.x;
    const int swz = (bid & 7) * (NBLK_FUSED_ / 8) + (bid >> 3);
    const int b   = swz / (4 * K_);
    const int rem = swz - b * (4 * K_);
    const int k   = rem >> 2;
    const int sg  = rem & 3;
    const int bk  = b * K_ + k;
    const int r0  = sg * TH_;

    // ---- class mean from stats partials (uniform -> SGPRs) ----
    float s0 = 0.f, s1 = 0.f, s2 = 0.f, s3 = 0.f;
#pragma unroll
    for (int c = 0; c < SCH_; ++c) {
        const float* p = ws + c * 4 * BK_;
        s0 += p[bk]; s1 += p[BK_ + bk]; s2 += p[2*BK_ + bk]; s3 += p[3*BK_ + bk];
    }
    const float dnv = s0 + 1e-5f * (float)HW_;
    const float c0 = s1 / dnv, c1 = s2 / dnv, c2 = s3 / dnv;
    const float tc0 = rfl(2.f * c0), tc1 = rfl(2.f * c1), tc2 = rfl(2.f * c2);
    const float m2v = rfl(c0*c0 + c1*c1 + c2*c2);

    const float* lb  = labels + (size_t)bk * HW_;
    const float* i0p = inputs + (size_t)b * 3 * HW_;
    const float* i1p = i0p + HW_;
    const float* i2p = i1p + HW_;

    __shared__ float sv[2][BATCH_][W_ + 8];   // pads [0..3], [W+4..W+7]
    if (x < 128) {                            // 2 buf x 8 rows x 8 pad cols
        const int bu = x >> 6, j = (x >> 3) & 7, p = x & 7;
        const int col = (p < 4) ? p : (W_ + p);
        sv[bu][j][col] = 0.f;
    }

    // ---- prologue state ----
    float ring[8], PL[8], PW[8];
#pragma unroll
    for (int i = 0; i < 8; ++i) {             // rows r0-4 .. r0+3
        const int gr = r0 - 4 + i;
        ring[i] = (gr >= 0) ? lb[gr * W_ + x] : 0.f;
    }
#pragma unroll
    for (int i = 0; i < 8; ++i)               // rows r0+4 .. r0+11 (<=203, in range)
        PL[i] = lb[(r0 + 4 + i) * W_ + x];
#pragma unroll
    for (int i = 0; i < 8; ++i) {             // weights rows r0 .. r0+7
        const int r = r0 + i;
        const float a0 = i0p[r * W_ + x], a1 = i1p[r * W_ + x], a2 = i2p[r * W_ + x];
        const float d = fmaf(a0, a0 - tc0, fmaf(a1, a1 - tc1, fmaf(a2, a2 - tc2, m2v)));
        PW[i] = __expf(-d * d);               // SIGMA_2 = 1
    }
    __syncthreads();                          // pads visible

    float num = 0.f, den = 0.f;
#pragma unroll 1
    for (int bt = 0; bt < TH_ / BATCH_; ++bt) {
        const int R = r0 + bt * BATCH_;
        const int bf = bt & 1;
        // ---- 1. issue next-batch loads (consumed after the barrier) ----
        float NL[8];
#pragma unroll
        for (int i = 0; i < 8; ++i) {         // labels rows R+12..R+19, 0 if OOB
            const int gr = R + 12 + i;
            NL[i] = (gr < H_) ? lb[gr * W_ + x] : 0.f;
        }
        float a0v[8], a1v[8], a2v[8];
#pragma unroll
        for (int i = 0; i < 8; ++i) {         // inputs rows R+8..R+15 (clamped; OOB values unused)
            int r = R + 8 + i; r = (r < H_) ? r : H_ - 1;
            a0v[i] = i0p[r * W_ + x]; a1v[i] = i1p[r * W_ + x]; a2v[i] = i2p[r * W_ + x];
        }
        // ---- 2. vertical 9-tap for 8 rows from ring||PL -> LDS ----
#pragma unroll
        for (int j = 0; j < 8; ++j) {
            const float v = fmaf(G4T, CAT(j) + CAT(j+8),
                            fmaf(G3T, CAT(j+1) + CAT(j+7),
                            fmaf(G2T, CAT(j+2) + CAT(j+6),
                            fmaf(G1T, CAT(j+3) + CAT(j+5), CAT(j+4)))));
            sv[bf][j][4 + x] = v;
        }
        // ---- 3. one barrier per batch ----
        __syncthreads();
        // ---- 4. h-blur + combine for 8 rows ----
#pragma unroll
        for (int j = 0; j < 8; ++j) {
            const float* s = &sv[bf][j][x];
            const float bl = fmaf(G4T, s[0] + s[8],
                             fmaf(G3T, s[1] + s[7],
                             fmaf(G2T, s[2] + s[6],
                             fmaf(G1T, s[3] + s[5], s[4]))));
            const float t = PW[j] * bl;
            den += t;
            num = fmaf(CAT(j+4), t, num);     // raw label at row R+j
        }
        // ---- 5. next weights + rotate state ----
#pragma unroll
        for (int i = 0; i < 8; ++i) {
            const float d = fmaf(a0v[i], a0v[i] - tc0,
                            fmaf(a1v[i], a1v[i] - tc1,
                            fmaf(a2v[i], a2v[i] - tc2, m2v)));
            const float w = __expf(-d * d);
            ring[i] = PL[i]; PL[i] = NL[i]; PW[i] = w;
        }
    }

    // ---- block reduce + last-block finalize ----
    const int widx = x >> 6, lane = x & 63;
    for (int o = 32; o > 0; o >>= 1) { num += __shfl_down(num, o); den += __shfl_down(den, o); }
    __shared__ float rb[4][2];
    __shared__ unsigned sdone;
    __syncthreads();
    if (lane == 0) { rb[widx][0] = num; rb[widx][1] = den; }
    __syncthreads();
    if (x == 0) {
        const float fn = rb[0][0] + rb[1][0] + rb[2][0] + rb[3][0];
        const float fd = rb[0][1] + rb[1][1] + rb[2][1] + rb[3][1];
        float2* nd2 = (float2*)(ws + WS_ND_);
        nd2[k * 64 + b * 4 + sg] = make_float2(fn, fd);
        __threadfence();
        sdone = atomicAdd((unsigned*)(ws + WS_CNT_), 1u);
    }
    __syncthreads();
    if (sdone == (unsigned)(NBLK_FUSED_ - 1)) {
        __threadfence();
        if (x < 64) {
            float term = 0.f;
            if (x < K_) {
                const float2* nd2 = (const float2*)(ws + WS_ND_);
                float ns = 0.f, ds = 0.f;
                for (int i = 0; i < 64; ++i) {
                    const float2 v = nd2[x * 64 + i];
                    ns += v.x; ds += v.y;
                }
                term = fabsf(ns / (ds + 1e-6f));
            }
            for (int o = 32; o > 0; o >>= 1) term += __shfl_down(term, o);
            if (x == 0) out[0] = (float)K_ - term;
        }
    }
}

extern "C" void kernel_launch(void* const* d_in, const int* in_sizes, int n_in,
                              void* d_out, int out_size, void* d_ws, size_t ws_size,
                              hipStream_t stream) {
    const float* labels = (const float*)d_in[0];
    const float* inputs = (const float*)d_in[1];
    float* ws = (float*)d_ws;   // needs WS_CNT_+1 floats ~= 92 KB

    stats_k<<<dim3(SCH_, K_ / KT_, B_), 256, 0, stream>>>(labels, inputs, ws);
    fused_k<<<NBLK_FUSED_, 256, 0, stream>>>(labels, inputs, ws, (float*)d_out);
}

// Round 8
// 196.974 us; speedup vs baseline: 1.2922x; 1.0012x over previous
//
#include <hip/hip_runtime.h>

#define B_ 16
#define K_ 20
#define H_ 256
#define W_ 256
#define HW_ (H_*W_)
#define BK_ (B_*K_)
#define TH_ 64          // rows per BLOCK strip (4 strips/image)
#define BATCH_ 8        // rows per barrier phase
#define KT_ 5           // classes per stats block
#define SCH_ 16         // stats row-chunks (16 rows each) -> 1024 blocks
#define NBLK_FUSED_ (4*K_*B_)   // fused grid = 1280 blocks

// ws layout (floats): statsP [SCH_][4][BK_] | ndP [NBLK][2] | cnt  (~92 KB)
#define WS_ND_   (SCH_*4*BK_)
#define WS_CNT_  (WS_ND_ + 2*NBLK_FUSED_)

// Gaussian taps exp(-d^2/50), d=1..4 (symmetric: 4 distinct + center 1.0)
#define G1T 0.980198673f
#define G2T 0.923116346f
#define G3T 0.835270211f
#define G4T 0.726149037f

__device__ __forceinline__ float rfl(float v) {   // force value into SGPR
    return __int_as_float(__builtin_amdgcn_readfirstlane(__float_as_int(v)));
}

// ---------------------------------------------------------------------------
// stats_k: per-(b,k) sums of labels and labels*inputs_c as per-chunk partials.
// grid (SCH_=16, K_/KT_=4, B_=16) = 1024 blocks. Batched float4 loads.
// ---------------------------------------------------------------------------
__global__ __launch_bounds__(256) void stats_k(const float* __restrict__ labels,
                                               const float* __restrict__ inputs,
                                               float* __restrict__ ws) {
    const int x = threadIdx.x;
    const int chunk = blockIdx.x;
    const int kt = blockIdx.y;
    const int b  = blockIdx.z;
    const int k0 = kt * KT_;
    if (chunk == 0 && kt == 0 && b == 0 && x == 0)
        ((unsigned*)(ws + WS_CNT_))[0] = 0u;   // reset fused completion counter

    const int cbase = chunk * (16 * W_ / 4);
    const float4* in0 = (const float4*)inputs + (size_t)b * 3 * (HW_/4) + cbase;
    const float4* in1 = in0 + (HW_/4);
    const float4* in2 = in1 + (HW_/4);
    const float4* lb  = (const float4*)labels + (size_t)(b * K_ + k0) * (HW_/4) + cbase;

    float acc[KT_][4];
#pragma unroll
    for (int kk = 0; kk < KT_; ++kk)
        acc[kk][0] = acc[kk][1] = acc[kk][2] = acc[kk][3] = 0.f;

#pragma unroll
    for (int it = 0; it < 4; ++it) {
        const int idx = it * 256 + x;
        const float4 a0 = in0[idx];
        const float4 a1 = in1[idx];
        const float4 a2 = in2[idx];
        float4 lv[KT_];
#pragma unroll
        for (int kk = 0; kk < KT_; ++kk) lv[kk] = lb[kk * (HW_/4) + idx];
#pragma unroll
        for (int kk = 0; kk < KT_; ++kk) {
            const float4 l = lv[kk];
            acc[kk][0] += (l.x + l.y) + (l.z + l.w);
            acc[kk][1] += fmaf(l.w, a0.w, fmaf(l.z, a0.z, fmaf(l.y, a0.y, l.x * a0.x)));
            acc[kk][2] += fmaf(l.w, a1.w, fmaf(l.z, a1.z, fmaf(l.y, a1.y, l.x * a1.x)));
            acc[kk][3] += fmaf(l.w, a2.w, fmaf(l.z, a2.z, fmaf(l.y, a2.y, l.x * a2.x)));
        }
    }

#pragma unroll
    for (int kk = 0; kk < KT_; ++kk)
#pragma unroll
        for (int q = 0; q < 4; ++q)
            for (int o = 32; o > 0; o >>= 1)
                acc[kk][q] += __shfl_down(acc[kk][q], o);

    __shared__ float sred[4][KT_][4];
    const int widx = x >> 6, lane = x & 63;
    if (lane == 0)
#pragma unroll
        for (int kk = 0; kk < KT_; ++kk)
#pragma unroll
            for (int q = 0; q < 4; ++q) sred[widx][kk][q] = acc[kk][q];
    __syncthreads();
    if (x < KT_ * 4) {
        const int kk = x >> 2, q = x & 3;
        const float v = sred[0][kk][q] + sred[1][kk][q] + sred[2][kk][q] + sred[3][kk][q];
        ws[(chunk * 4 + q) * BK_ + b * K_ + k0 + kk] = v;
    }
}

// ---------------------------------------------------------------------------
// fused_k, scalar-column ADJOINT form, 8-row batched phases with a RAW
// s_barrier (lgkmcnt-only drain): global prefetch loads SURVIVE the barrier,
// so the compiler's automatic vmcnt(N) wait at first-use acts as a counted
// wait (T4), not a drain. __syncthreads() would emit s_waitcnt vmcnt(0)
// before s_barrier and kill the pipeline (measured: rounds 6/7 stuck at
// ~26% VALUBusy).
//   num = sum (l*w)*blur(l),  den = sum w*blur(l)   (G symmetric, zero-pad)
// Vertical 9-tap for 8 output rows needs rows R-4..R+11 = ring[8] || PL[8],
// all in registers. LDS: double-buffered 8-row h-blur staging, stride-1.
// Double-buffer is safe across raw barriers: max wave skew = 1 phase, and
// each wave's own lgkmcnt(0) drains its reads before it can pass a barrier.
// grid: 1280 blocks 1D, bijective XCD-chunk swizzle (1280 % 8 == 0).
// ---------------------------------------------------------------------------
#define CAT(m) (((m) < 8) ? ring[(m)&7] : PL[(m)&7])

__global__ __launch_bounds__(256) void fused_k(const float* __restrict__ labels,
                                               const float* __restrict__ inputs,
                                               float* __restrict__ ws,
                                               float* __restrict__ out) {
    const int x = threadIdx.x;            // column
    const int bid = blockIdx.x;
    const int swz = (bid & 7) * (NBLK_FUSED_ / 8) + (bid >> 3);
    const int b   = swz / (4 * K_);
    const int rem = swz - b * (4 * K_);
    const int k   = rem >> 2;
    const int sg  = rem & 3;
    const int bk  = b * K_ + k;
    const int r0  = sg * TH_;

    // ---- class mean from stats partials (uniform -> SGPRs) ----
    float s0 = 0.f, s1 = 0.f, s2 = 0.f, s3 = 0.f;
#pragma unroll
    for (int c = 0; c < SCH_; ++c) {
        const float* p = ws + c * 4 * BK_;
        s0 += p[bk]; s1 += p[BK_ + bk]; s2 += p[2*BK_ + bk]; s3 += p[3*BK_ + bk];
    }
    const float dnv = s0 + 1e-5f * (float)HW_;
    const float c0 = s1 / dnv, c1 = s2 / dnv, c2 = s3 / dnv;
    const float tc0 = rfl(2.f * c0), tc1 = rfl(2.f * c1), tc2 = rfl(2.f * c2);
    const float m2v = rfl(c0*c0 + c1*c1 + c2*c2);

    const float* lb  = labels + (size_t)bk * HW_;
    const float* i0p = inputs + (size_t)b * 3 * HW_;
    const float* i1p = i0p + HW_;
    const float* i2p = i1p + HW_;

    __shared__ float sv[2][BATCH_][W_ + 8];   // pads [0..3], [W+4..W+7]
    if (x < 128) {                            // 2 buf x 8 rows x 8 pad cols
        const int bu = x >> 6, j = (x >> 3) & 7, p = x & 7;
        const int col = (p < 4) ? p : (W_ + p);
        sv[bu][j][col] = 0.f;
    }

    // ---- prologue state ----
    float ring[8], PL[8], PW[8];
#pragma unroll
    for (int i = 0; i < 8; ++i) {             // rows r0-4 .. r0+3
        const int gr = r0 - 4 + i;
        ring[i] = (gr >= 0) ? lb[gr * W_ + x] : 0.f;
    }
#pragma unroll
    for (int i = 0; i < 8; ++i)               // rows r0+4 .. r0+11 (<=203, in range)
        PL[i] = lb[(r0 + 4 + i) * W_ + x];
#pragma unroll
    for (int i = 0; i < 8; ++i) {             // weights rows r0 .. r0+7
        const int r = r0 + i;
        const float a0 = i0p[r * W_ + x], a1 = i1p[r * W_ + x], a2 = i2p[r * W_ + x];
        const float d = fmaf(a0, a0 - tc0, fmaf(a1, a1 - tc1, fmaf(a2, a2 - tc2, m2v)));
        PW[i] = __expf(-d * d);               // SIGMA_2 = 1
    }
    __syncthreads();                          // pads visible (full sync, once)

    float num = 0.f, den = 0.f;
#pragma unroll 1
    for (int bt = 0; bt < TH_ / BATCH_; ++bt) {
        const int R = r0 + bt * BATCH_;
        const int bf = bt & 1;
        // ---- 1. issue next-batch loads (stay in flight across the barrier,
        //         consumed at step 5 -> compiler emits counted vmcnt there) --
        float NL[8];
#pragma unroll
        for (int i = 0; i < 8; ++i) {         // labels rows R+12..R+19, 0 if OOB
            const int gr = R + 12 + i;
            NL[i] = (gr < H_) ? lb[gr * W_ + x] : 0.f;
        }
        float a0v[8], a1v[8], a2v[8];
#pragma unroll
        for (int i = 0; i < 8; ++i) {         // inputs rows R+8..R+15 (clamped; OOB unused)
            int r = R + 8 + i; r = (r < H_) ? r : H_ - 1;
            a0v[i] = i0p[r * W_ + x]; a1v[i] = i1p[r * W_ + x]; a2v[i] = i2p[r * W_ + x];
        }
        // ---- 2. vertical 9-tap for 8 rows from ring||PL -> LDS ----
#pragma unroll
        for (int j = 0; j < 8; ++j) {
            const float v = fmaf(G4T, CAT(j) + CAT(j+8),
                            fmaf(G3T, CAT(j+1) + CAT(j+7),
                            fmaf(G2T, CAT(j+2) + CAT(j+6),
                            fmaf(G1T, CAT(j+3) + CAT(j+5), CAT(j+4)))));
            sv[bf][j][4 + x] = v;
        }
        // ---- 3. RAW barrier: drain LDS only; global loads stay in flight ----
        asm volatile("s_waitcnt lgkmcnt(0)" ::: "memory");
        __builtin_amdgcn_s_barrier();
        asm volatile("" ::: "memory");
        // ---- 4. h-blur + combine for 8 rows ----
#pragma unroll
        for (int j = 0; j < 8; ++j) {
            const float* s = &sv[bf][j][x];
            const float bl = fmaf(G4T, s[0] + s[8],
                             fmaf(G3T, s[1] + s[7],
                             fmaf(G2T, s[2] + s[6],
                             fmaf(G1T, s[3] + s[5], s[4]))));
            const float t = PW[j] * bl;
            den += t;
            num = fmaf(CAT(j+4), t, num);     // raw label at row R+j
        }
        // ---- 5. next weights + rotate state (first use of step-1 loads) ----
#pragma unroll
        for (int i = 0; i < 8; ++i) {
            const float d = fmaf(a0v[i], a0v[i] - tc0,
                            fmaf(a1v[i], a1v[i] - tc1,
                            fmaf(a2v[i], a2v[i] - tc2, m2v)));
            const float w = __expf(-d * d);
            ring[i] = PL[i]; PL[i] = NL[i]; PW[i] = w;
        }
    }

    // ---- block reduce + last-block finalize ----
    const int widx = x >> 6, lane = x & 63;
    for (int o = 32; o > 0; o >>= 1) { num += __shfl_down(num, o); den += __shfl_down(den, o); }
    __shared__ float rb[4][2];
    __shared__ unsigned sdone;
    __syncthreads();
    if (lane == 0) { rb[widx][0] = num; rb[widx][1] = den; }
    __syncthreads();
    if (x == 0) {
        const float fn = rb[0][0] + rb[1][0] + rb[2][0] + rb[3][0];
        const float fd = rb[0][1] + rb[1][1] + rb[2][1] + rb[3][1];
        float2* nd2 = (float2*)(ws + WS_ND_);
        nd2[k * 64 + b * 4 + sg] = make_float2(fn, fd);
        __threadfence();
        sdone = atomicAdd((unsigned*)(ws + WS_CNT_), 1u);
    }
    __syncthreads();
    if (sdone == (unsigned)(NBLK_FUSED_ - 1)) {
        __threadfence();
        if (x < 64) {
            float term = 0.f;
            if (x < K_) {
                const float2* nd2 = (const float2*)(ws + WS_ND_);
                float ns = 0.f, ds = 0.f;
                for (int i = 0; i < 64; ++i) {
                    const float2 v = nd2[x * 64 + i];
                    ns += v.x; ds += v.y;
                }
                term = fabsf(ns / (ds + 1e-6f));
            }
            for (int o = 32; o > 0; o >>= 1) term += __shfl_down(term, o);
            if (x == 0) out[0] = (float)K_ - term;
        }
    }
}

extern "C" void kernel_launch(void* const* d_in, const int* in_sizes, int n_in,
                              void* d_out, int out_size, void* d_ws, size_t ws_size,
                              hipStream_t stream) {
    const float* labels = (const float*)d_in[0];
    const float* inputs = (const float*)d_in[1];
    float* ws = (float*)d_ws;   // needs WS_CNT_+1 floats ~= 92 KB

    stats_k<<<dim3(SCH_, K_ / KT_, B_), 256, 0, stream>>>(labels, inputs, ws);
    fused_k<<<NBLK_FUSED_, 256, 0, stream>>>(labels, inputs, ws, (float*)d_out);
}